// Round 6
// baseline (87.642 us; speedup 1.0000x reference)
//
#include <hip/hip_runtime.h>

#define NMS_T    0.7f
#define SCORE_T  0.05f
#define MIN_SZ   0.001f
#define MAXK     250
#define NEGV     -1e30f
#define NB       2048
#define NIMG     8
#define NT       512
#define NW       (NT / 64)

typedef unsigned long long u64;
typedef unsigned int u32;

// inverse of the order-preserving float->u32 descending-sort transform
__device__ __forceinline__ float sp_from_key(u32 inv) {
  return (inv & 0x80000000u) ? __uint_as_float(inv)
                             : __uint_as_float((~inv) ^ 0x80000000u);
}

// exact reference arithmetic; kept/other box area recomputed (bit-identical)
__device__ __forceinline__ bool iou_gt(const float4 a, float aa, const float4 b) {
  float ba = (b.z - b.x) * (b.w - b.y);
  float xx1 = fmaxf(a.x, b.x);
  float yy1 = fmaxf(a.y, b.y);
  float xx2 = fminf(a.z, b.z);
  float yy2 = fminf(a.w, b.w);
  float inter = fmaxf(xx2 - xx1, 0.0f) * fmaxf(yy2 - yy1, 0.0f);
  float denom = aa + ba - inter + 1e-12f;  // f32 add commutative
  return (inter / denom) > NMS_T;          // IEEE f32 divide
}

__device__ __forceinline__ u64 shflx64(u64 v, int mask) {
  return (u64)__shfl_xor((unsigned long long)v, mask, 64);
}

__device__ __forceinline__ u64 ce_min(u64 a, u64 b) { return a < b ? a : b; }
__device__ __forceinline__ u64 ce_max(u64 a, u64 b) { return a > b ? a : b; }

__global__ __launch_bounds__(NT) void filter_rois_kernel(
    const float* __restrict__ proposals,
    const float* __restrict__ scores,
    float* __restrict__ out) {
  __shared__ u64 s_key[NB];            // 16 KB (inv<<32 | orig local idx)
  __shared__ float4 c_box[NB];         // 32 KB sorted candidate boxes
  __shared__ float4 s_kbox[MAXK + 6];  // kept boxes (score order)
  __shared__ float s_ksc[MAXK + 6];
  __shared__ int s_wcnt[32];
  __shared__ int s_nv;
  __shared__ u64 s_pm[NW][64];
  __shared__ u64 s_bw[NW];
  __shared__ int s_nk;

  const int tid = threadIdx.x;
  const int img = blockIdx.x;
  const int w = tid >> 6;
  const int lane = tid & 63;

  // ---- stage 0/1/2: transform + validity; keys in registers ----
  u32 inv_r[4];
  int rank_r[4];
  bool valid_r[4];
  for (int r = 0; r < 4; ++r) {
    int l = r * NT + tid;             // chunk (r*8+w), lane asc == idx asc
    int g = img * NB + l;
    float4 p = reinterpret_cast<const float4*>(proposals)[g];
    float s = scores[g];
    double e = exp(-(double)s);
    float sig = (float)(1.0 / (1.0 + e));
    float sp = sig * 2.0f - 1.0f;
    float x1 = fminf(fmaxf(p.x, 0.0f), 512.0f);
    float y1 = fminf(fmaxf(p.y, 0.0f), 512.0f);
    float x2 = fminf(fmaxf(p.z, 0.0f), 512.0f);
    float y2 = fminf(fmaxf(p.w, 0.0f), 512.0f);
    bool valid = (sp >= SCORE_T) && ((x2 - x1) >= MIN_SZ) && ((y2 - y1) >= MIN_SZ);
    u32 u = __float_as_uint(valid ? sp : NEGV);
    u32 ob = (u & 0x80000000u) ? ~u : (u | 0x80000000u);
    inv_r[r] = ~ob;                   // ascending inv == descending score
    valid_r[r] = valid;
    u64 b = __ballot(valid);
    if (lane == 0) s_wcnt[r * 8 + w] = (int)__popcll(b);
    rank_r[r] = (int)__popcll(b & ((1ull << lane) - 1ull));
  }
  __syncthreads();

  // exclusive prefix over the 32 chunk counts
  if (tid < 32) {
    int v = s_wcnt[tid];
    int inc = v;
    for (int d = 1; d < 32; d <<= 1) {
      int t2 = __shfl_up(inc, d, 64);
      if (tid >= d) inc += t2;
    }
    s_wcnt[tid] = inc - v;
    if (tid == 31) s_nv = inc;
  }
  __syncthreads();

  // stable scatter of valid keys + tail fill
  for (int r = 0; r < 4; ++r) {
    if (valid_r[r]) {
      int l = r * NT + tid;
      int pos = s_wcnt[r * 8 + w] + rank_r[r];
      s_key[pos] = ((u64)inv_r[r] << 32) | (u32)l;
    }
  }
  const int Nv = s_nv;
  const int n = (Nv <= 1024) ? 1024 : NB;
  for (int i2 = Nv + tid; i2 < n; i2 += NT) s_key[i2] = ~0ull;
  __syncthreads();

  // ---- stable sort (ascending 64-bit key == descending score) ----
  if (Nv <= 1024) {
    const u32 i0 = 2 * tid, i1 = 2 * tid + 1;
    u64 e0 = s_key[i0], e1 = s_key[i1];
    for (u32 k = 2; k <= 1024; k <<= 1) {
      for (u32 j = k >> 1; j >= 1; j >>= 1) {
        bool asc = ((i0 & k) == 0);
        if (j == 1) {
          u64 lo = ce_min(e0, e1), hi = ce_max(e0, e1);
          e0 = asc ? lo : hi;
          e1 = asc ? hi : lo;
        } else if (j <= 64) {
          bool lower = ((i0 & j) == 0);
          bool takemin = (lower == asc);
          u64 p0 = shflx64(e0, (int)(j >> 1));
          u64 p1 = shflx64(e1, (int)(j >> 1));
          e0 = takemin ? ce_min(e0, p0) : ce_max(e0, p0);
          e1 = takemin ? ce_min(e1, p1) : ce_max(e1, p1);
        } else {
          __syncthreads();
          s_key[i0] = e0;
          s_key[i1] = e1;
          __syncthreads();
          u64 p0 = s_key[i0 ^ j], p1 = s_key[i1 ^ j];
          bool lower = ((i0 & j) == 0);
          bool takemin = (lower == asc);
          e0 = takemin ? ce_min(e0, p0) : ce_max(e0, p0);
          e1 = takemin ? ce_min(e1, p1) : ce_max(e1, p1);
        }
      }
    }
    __syncthreads();
    s_key[i0] = e0;
    s_key[i1] = e1;
  } else {
    for (u32 k = 2; k <= NB; k <<= 1) {
      for (u32 j = k >> 1; j > 0; j >>= 1) {
        for (u32 i = tid; i < NB; i += NT) {
          u32 ixj = i ^ j;
          if (ixj > i) {
            u64 a = s_key[i];
            u64 b = s_key[ixj];
            bool up = ((i & k) == 0);
            bool sw = up ? (a > b) : (a < b);
            if (sw) { s_key[i] = b; s_key[ixj] = a; }
          }
        }
        __syncthreads();
      }
    }
  }
  if (tid == 0) s_nk = 0;
  __syncthreads();

  // ---- apply sorted permutation ONCE: re-derive clipped boxes (L2-hot) ----
  const int nPad = (Nv + 63) & ~63;
  for (int i = tid; i < nPad; i += NT) {
    float4 bo = make_float4(0.f, 0.f, 0.f, 0.f);
    if (i < Nv) {
      u32 idx = (u32)(s_key[i] & 0xffffffffu);
      float4 p = reinterpret_cast<const float4*>(proposals)[img * NB + (int)idx];
      bo.x = fminf(fmaxf(p.x, 0.0f), 512.0f);
      bo.y = fminf(fmaxf(p.y, 0.0f), 512.0f);
      bo.z = fminf(fmaxf(p.z, 0.0f), 512.0f);
      bo.w = fminf(fmaxf(p.w, 0.0f), 512.0f);
    }
    c_box[i] = bo;
  }
  __syncthreads();

  // ---- stage 3: chunk-parallel greedy NMS (2 barriers/round) ----
  for (int t = 0; t * 64 < Nv; ++t) {
    const int nk = s_nk;               // visible: barrier ends previous round
    if (nk >= MAXK) break;             // uniform
    const int c0 = t * 64;
    const int ci = c0 + lane;
    const bool valid = ci < Nv;
    const float4 cb = c_box[ci];
    const float ca = (cb.z - cb.x) * (cb.w - cb.y);

    // (a) suppression vs kept list, split across waves
    bool sup = false;
    for (int j = w; j < nk; j += NW)
      sup = sup || iou_gt(cb, ca, s_kbox[j]);
    u64 bsup = __ballot(sup);
    if (lane == 0) s_bw[w] = bsup;

    // (b) within-chunk triangle, split across waves
    u64 pm = 0;
    for (int j = w; j < 64; j += NW) {
      if (j < lane && iou_gt(cb, ca, c_box[c0 + j]))
        pm |= 1ull << j;
    }
    s_pm[w][lane] = pm;
    __syncthreads();

    // wave 0: combine masks, bulk-keep sweep, append
    if (w == 0) {
      u64 m = 0;
      for (int q = 0; q < NW; ++q) m |= s_pm[q][lane];
      u64 supmask = 0;
      for (int q = 0; q < NW; ++q) supmask |= s_bw[q];
      u64 alive = __ballot(valid) & ~supmask;
      u64 m2 = m & alive;
      u64 kept = 0;
      while (alive) {
        m2 &= (alive | kept);
        u64 targets = __ballot(m2 != 0) & alive;
        if (!targets) { kept |= alive; break; }
        int tb = (int)__ffsll((unsigned long long)targets) - 1;
        u64 below = ((1ull << tb) - 1ull) & alive;
        kept |= below;
        alive &= ~below;
        u64 supnow = __ballot((m2 & kept) != 0);
        if (!((supnow >> tb) & 1ull)) kept |= (1ull << tb);
        alive &= ~(1ull << tb);
      }
      int space = MAXK - nk;
      int npc = (int)__popcll(kept);
      int nnew = npc < space ? npc : space;
      if ((kept >> lane) & 1ull) {
        int rank = (int)__popcll(kept & ((1ull << lane) - 1ull));
        if (rank < space) {
          s_kbox[nk + rank] = cb;
          s_ksc[nk + rank] = sp_from_key((u32)(s_key[ci] >> 32));
        }
      }
      if (lane == 0) s_nk = nk + nnew;
    }
    __syncthreads();
  }

  // ---- stage 4: top-250 (kept list already in score order) ----
  const int nk = s_nk;
  for (int o = tid; o < MAXK; o += NT) {
    float4 bo = make_float4(0.f, 0.f, 0.f, 0.f);
    float so = 0.0f, vo = 0.0f;
    if (o < nk) {
      bo = s_kbox[o];
      so = s_ksc[o];
      vo = 1.0f;
    }
    reinterpret_cast<float4*>(out)[img * MAXK + o] = bo;          // boxes [8,250,4]
    out[NIMG * MAXK * 4 + img * MAXK + o] = so;                   // scores [8,250]
    out[NIMG * MAXK * 4 + NIMG * MAXK + img * MAXK + o] = vo;     // valid [8,250]
  }
}

extern "C" void kernel_launch(void* const* d_in, const int* in_sizes, int n_in,
                              void* d_out, int out_size, void* d_ws, size_t ws_size,
                              hipStream_t stream) {
  const float* proposals = (const float*)d_in[0];
  const float* scores    = (const float*)d_in[1];
  float* out             = (float*)d_out;
  filter_rois_kernel<<<dim3(NIMG), dim3(NT), 0, stream>>>(proposals, scores, out);
}

// Round 7
// 85.092 us; speedup vs baseline: 1.0300x; 1.0300x over previous
//
#include <hip/hip_runtime.h>

#define NMS_T    0.7f
#define SCORE_T  0.05f
#define MIN_SZ   0.001f
#define MAXK     250
#define NEGV     -1e30f
#define NB       2048
#define NIMG     8
#define NT       512
#define NW       (NT / 64)

typedef unsigned long long u64;
typedef unsigned int u32;

// inverse of the order-preserving float->u32 descending-sort transform
__device__ __forceinline__ float sp_from_key(u32 inv) {
  return (inv & 0x80000000u) ? __uint_as_float(inv)
                             : __uint_as_float((~inv) ^ 0x80000000u);
}

// exact reference arithmetic; other box area recomputed (bit-identical)
__device__ __forceinline__ bool iou_gt(const float4 a, float aa, const float4 b) {
  float ba = (b.z - b.x) * (b.w - b.y);
  float xx1 = fmaxf(a.x, b.x);
  float yy1 = fmaxf(a.y, b.y);
  float xx2 = fminf(a.z, b.z);
  float yy2 = fminf(a.w, b.w);
  float inter = fmaxf(xx2 - xx1, 0.0f) * fmaxf(yy2 - yy1, 0.0f);
  float denom = aa + ba - inter + 1e-12f;  // f32 add commutative
  return (inter / denom) > NMS_T;          // IEEE f32 divide
}

__device__ __forceinline__ u64 shflx64(u64 v, int mask) {
  return (u64)__shfl_xor((unsigned long long)v, mask, 64);
}

__device__ __forceinline__ u64 ce_min(u64 a, u64 b) { return a < b ? a : b; }
__device__ __forceinline__ u64 ce_max(u64 a, u64 b) { return a > b ? a : b; }

__global__ __launch_bounds__(NT) void filter_rois_kernel(
    const float* __restrict__ proposals,
    const float* __restrict__ scores,
    float* __restrict__ out) {
  __shared__ u64 s_key[NB];            // 16 KB canonical keys (inv<<32 | idx)
  __shared__ u64 s_key2[1024];         // 8 KB ping-pong buffer for sort
  __shared__ float4 c_box[NB];         // 32 KB sorted candidate boxes
  __shared__ float4 s_kbox[MAXK + 6];  // kept boxes (score order)
  __shared__ float s_ksc[MAXK + 6];
  __shared__ int s_wcnt[32];
  __shared__ int s_nv;
  __shared__ u64 s_pm[NW][64];
  __shared__ u64 s_bw[NW];
  __shared__ int s_nk;

  const int tid = threadIdx.x;
  const int img = blockIdx.x;
  const int w = tid >> 6;
  const int lane = tid & 63;

  // ---- stage 0/1/2: transform + validity; keys in registers ----
  u32 inv_r[4];
  int rank_r[4];
  bool valid_r[4];
  for (int r = 0; r < 4; ++r) {
    int l = r * NT + tid;             // chunk (r*8+w), lane asc == idx asc
    int g = img * NB + l;
    float4 p = reinterpret_cast<const float4*>(proposals)[g];
    float s = scores[g];
    double e = exp(-(double)s);
    float sig = (float)(1.0 / (1.0 + e));
    float sp = sig * 2.0f - 1.0f;
    float x1 = fminf(fmaxf(p.x, 0.0f), 512.0f);
    float y1 = fminf(fmaxf(p.y, 0.0f), 512.0f);
    float x2 = fminf(fmaxf(p.z, 0.0f), 512.0f);
    float y2 = fminf(fmaxf(p.w, 0.0f), 512.0f);
    bool valid = (sp >= SCORE_T) && ((x2 - x1) >= MIN_SZ) && ((y2 - y1) >= MIN_SZ);
    u32 u = __float_as_uint(valid ? sp : NEGV);
    u32 ob = (u & 0x80000000u) ? ~u : (u | 0x80000000u);
    inv_r[r] = ~ob;                   // ascending inv == descending score
    valid_r[r] = valid;
    u64 b = __ballot(valid);
    if (lane == 0) s_wcnt[r * 8 + w] = (int)__popcll(b);
    rank_r[r] = (int)__popcll(b & ((1ull << lane) - 1ull));
  }
  __syncthreads();

  // exclusive prefix over the 32 chunk counts
  if (tid < 32) {
    int v = s_wcnt[tid];
    int inc = v;
    for (int d = 1; d < 32; d <<= 1) {
      int t2 = __shfl_up(inc, d, 64);
      if (tid >= d) inc += t2;
    }
    s_wcnt[tid] = inc - v;
    if (tid == 31) s_nv = inc;
  }
  __syncthreads();

  // stable scatter of valid keys + tail fill
  for (int r = 0; r < 4; ++r) {
    if (valid_r[r]) {
      int l = r * NT + tid;
      int pos = s_wcnt[r * 8 + w] + rank_r[r];
      s_key[pos] = ((u64)inv_r[r] << 32) | (u32)l;
    }
  }
  const int Nv = s_nv;
  const int n = (Nv <= 1024) ? 1024 : NB;
  for (int i2 = Nv + tid; i2 < n; i2 += NT) s_key[i2] = ~0ull;
  if (tid == 0) s_nk = 0;
  __syncthreads();

  // ---- stable sort (ascending 64-bit key == descending score) ----
  if (Nv <= 1024) {
    // register bitonic, 2 keys/thread; j<=64 shuffles; j>=128 LDS ping-pong
    const u32 i0 = 2 * tid, i1 = 2 * tid + 1;
    u64 e0 = s_key[i0], e1 = s_key[i1];
    int cur = 1;                       // first LDS pass writes s_key2
    for (u32 k = 2; k <= 1024; k <<= 1) {
      for (u32 j = k >> 1; j >= 1; j >>= 1) {
        bool asc = ((i0 & k) == 0);
        if (j == 1) {
          u64 lo = ce_min(e0, e1), hi = ce_max(e0, e1);
          e0 = asc ? lo : hi;
          e1 = asc ? hi : lo;
        } else if (j <= 64) {
          bool lower = ((i0 & j) == 0);
          bool takemin = (lower == asc);
          u64 p0 = shflx64(e0, (int)(j >> 1));
          u64 p1 = shflx64(e1, (int)(j >> 1));
          e0 = takemin ? ce_min(e0, p0) : ce_max(e0, p0);
          e1 = takemin ? ce_min(e1, p1) : ce_max(e1, p1);
        } else {
          // single-barrier LDS pass: write other buffer, barrier, read it
          u64* wb = cur ? s_key2 : s_key;
          wb[i0] = e0;
          wb[i1] = e1;
          __syncthreads();
          u64 p0 = wb[i0 ^ j], p1 = wb[i1 ^ j];
          bool lower = ((i0 & j) == 0);
          bool takemin = (lower == asc);
          e0 = takemin ? ce_min(e0, p0) : ce_max(e0, p0);
          e1 = takemin ? ce_min(e1, p1) : ce_max(e1, p1);
          cur ^= 1;
        }
      }
    }
    // fused epilogue: issue gathers for our 2 sorted positions NOW
    // (overlaps global latency with the pre-write barrier)
    float4 p0 = make_float4(0.f, 0.f, 0.f, 0.f);
    float4 p1 = make_float4(0.f, 0.f, 0.f, 0.f);
    const bool v0 = (int)i0 < Nv, v1 = (int)i1 < Nv;
    if (v0) p0 = reinterpret_cast<const float4*>(proposals)[img * NB + (int)(e0 & 0xffffffffu)];
    if (v1) p1 = reinterpret_cast<const float4*>(proposals)[img * NB + (int)(e1 & 0xffffffffu)];
    __syncthreads();                   // protect last LDS-pass reads
    s_key[i0] = e0;
    s_key[i1] = e1;
    float4 b0 = make_float4(0.f, 0.f, 0.f, 0.f);
    float4 b1 = make_float4(0.f, 0.f, 0.f, 0.f);
    if (v0) {
      b0.x = fminf(fmaxf(p0.x, 0.0f), 512.0f);
      b0.y = fminf(fmaxf(p0.y, 0.0f), 512.0f);
      b0.z = fminf(fmaxf(p0.z, 0.0f), 512.0f);
      b0.w = fminf(fmaxf(p0.w, 0.0f), 512.0f);
    }
    if (v1) {
      b1.x = fminf(fmaxf(p1.x, 0.0f), 512.0f);
      b1.y = fminf(fmaxf(p1.y, 0.0f), 512.0f);
      b1.z = fminf(fmaxf(p1.z, 0.0f), 512.0f);
      b1.w = fminf(fmaxf(p1.w, 0.0f), 512.0f);
    }
    c_box[i0] = b0;
    c_box[i1] = b1;
    __syncthreads();
  } else {
    // rare fallback: plain LDS bitonic over 2048, then permutation apply
    for (u32 k = 2; k <= NB; k <<= 1) {
      for (u32 j = k >> 1; j > 0; j >>= 1) {
        for (u32 i = tid; i < NB; i += NT) {
          u32 ixj = i ^ j;
          if (ixj > i) {
            u64 a = s_key[i];
            u64 b = s_key[ixj];
            bool up = ((i & k) == 0);
            bool sw = up ? (a > b) : (a < b);
            if (sw) { s_key[i] = b; s_key[ixj] = a; }
          }
        }
        __syncthreads();
      }
    }
    const int nPad = (Nv + 63) & ~63;
    for (int i = tid; i < nPad; i += NT) {
      float4 bo = make_float4(0.f, 0.f, 0.f, 0.f);
      if (i < Nv) {
        u32 idx = (u32)(s_key[i] & 0xffffffffu);
        float4 p = reinterpret_cast<const float4*>(proposals)[img * NB + (int)idx];
        bo.x = fminf(fmaxf(p.x, 0.0f), 512.0f);
        bo.y = fminf(fmaxf(p.y, 0.0f), 512.0f);
        bo.z = fminf(fmaxf(p.z, 0.0f), 512.0f);
        bo.w = fminf(fmaxf(p.w, 0.0f), 512.0f);
      }
      c_box[i] = bo;
    }
    __syncthreads();
  }

  // ---- stage 3: chunk-parallel greedy NMS (2 barriers/round) ----
  for (int t = 0; t * 64 < Nv; ++t) {
    const int nk = s_nk;               // visible: barrier ends previous round
    if (nk >= MAXK) break;             // uniform
    const int c0 = t * 64;
    const int ci = c0 + lane;
    const bool valid = ci < Nv;
    const float4 cb = c_box[ci];
    const float ca = (cb.z - cb.x) * (cb.w - cb.y);

    // prefetch the 8 within-chunk triangle partners (8 loads in flight)
    float4 tb0 = c_box[c0 + w];
    float4 tb1 = c_box[c0 + w + 8];
    float4 tb2 = c_box[c0 + w + 16];
    float4 tb3 = c_box[c0 + w + 24];
    float4 tb4 = c_box[c0 + w + 32];
    float4 tb5 = c_box[c0 + w + 40];
    float4 tb6 = c_box[c0 + w + 48];
    float4 tb7 = c_box[c0 + w + 56];

    // (a) suppression vs kept list, split across waves, 4 loads in flight
    bool sup = false;
    int j = w;
    for (; j + 3 * NW < nk; j += 4 * NW) {
      float4 k0 = s_kbox[j];
      float4 k1 = s_kbox[j + NW];
      float4 k2 = s_kbox[j + 2 * NW];
      float4 k3 = s_kbox[j + 3 * NW];
      sup = sup | iou_gt(cb, ca, k0) | iou_gt(cb, ca, k1)
                | iou_gt(cb, ca, k2) | iou_gt(cb, ca, k3);
    }
    for (; j < nk; j += NW) sup = sup | iou_gt(cb, ca, s_kbox[j]);
    u64 bsup = __ballot(sup);
    if (lane == 0) s_bw[w] = bsup;

    // (b) within-chunk triangle (prefetched, static indices)
    u64 pm = 0;
    if (w + 0      < lane && iou_gt(cb, ca, tb0)) pm |= 1ull << (w + 0);
    if (w + 8      < lane && iou_gt(cb, ca, tb1)) pm |= 1ull << (w + 8);
    if (w + 16     < lane && iou_gt(cb, ca, tb2)) pm |= 1ull << (w + 16);
    if (w + 24     < lane && iou_gt(cb, ca, tb3)) pm |= 1ull << (w + 24);
    if (w + 32     < lane && iou_gt(cb, ca, tb4)) pm |= 1ull << (w + 32);
    if (w + 40     < lane && iou_gt(cb, ca, tb5)) pm |= 1ull << (w + 40);
    if (w + 48     < lane && iou_gt(cb, ca, tb6)) pm |= 1ull << (w + 48);
    if (w + 56     < lane && iou_gt(cb, ca, tb7)) pm |= 1ull << (w + 56);
    s_pm[w][lane] = pm;
    __syncthreads();

    // wave 0: combine masks, bulk-keep sweep, append
    if (w == 0) {
      u64 m = 0;
      for (int q = 0; q < NW; ++q) m |= s_pm[q][lane];
      u64 supmask = 0;
      for (int q = 0; q < NW; ++q) supmask |= s_bw[q];
      u64 alive = __ballot(valid) & ~supmask;
      u64 m2 = m & alive;
      u64 kept = 0;
      while (alive) {
        m2 &= (alive | kept);
        u64 targets = __ballot(m2 != 0) & alive;
        if (!targets) { kept |= alive; break; }
        int tb = (int)__ffsll((unsigned long long)targets) - 1;
        u64 below = ((1ull << tb) - 1ull) & alive;
        kept |= below;
        alive &= ~below;
        u64 supnow = __ballot((m2 & kept) != 0);
        if (!((supnow >> tb) & 1ull)) kept |= (1ull << tb);
        alive &= ~(1ull << tb);
      }
      int space = MAXK - nk;
      int npc = (int)__popcll(kept);
      int nnew = npc < space ? npc : space;
      if ((kept >> lane) & 1ull) {
        int rank = (int)__popcll(kept & ((1ull << lane) - 1ull));
        if (rank < space) {
          s_kbox[nk + rank] = cb;
          s_ksc[nk + rank] = sp_from_key((u32)(s_key[ci] >> 32));
        }
      }
      if (lane == 0) s_nk = nk + nnew;
    }
    __syncthreads();
  }

  // ---- stage 4: top-250 (kept list already in score order) ----
  const int nk = s_nk;
  for (int o = tid; o < MAXK; o += NT) {
    float4 bo = make_float4(0.f, 0.f, 0.f, 0.f);
    float so = 0.0f, vo = 0.0f;
    if (o < nk) {
      bo = s_kbox[o];
      so = s_ksc[o];
      vo = 1.0f;
    }
    reinterpret_cast<float4*>(out)[img * MAXK + o] = bo;          // boxes [8,250,4]
    out[NIMG * MAXK * 4 + img * MAXK + o] = so;                   // scores [8,250]
    out[NIMG * MAXK * 4 + NIMG * MAXK + img * MAXK + o] = vo;     // valid [8,250]
  }
}

extern "C" void kernel_launch(void* const* d_in, const int* in_sizes, int n_in,
                              void* d_out, int out_size, void* d_ws, size_t ws_size,
                              hipStream_t stream) {
  const float* proposals = (const float*)d_in[0];
  const float* scores    = (const float*)d_in[1];
  float* out             = (float*)d_out;
  filter_rois_kernel<<<dim3(NIMG), dim3(NT), 0, stream>>>(proposals, scores, out);
}